// Round 6
// baseline (746.754 us; speedup 1.0000x reference)
//
#include <hip/hip_runtime.h>

typedef unsigned short u16;
typedef unsigned int u32;
typedef __attribute__((ext_vector_type(8))) short short8;
typedef __attribute__((ext_vector_type(4))) float f32x4;

// Problem constants
#define N_B 2
#define N_S 1024
#define N_DIN 2048
#define N_DOUT 2048
#define N_H 8
#define N_DK 64
#define N_DV 128
#define N_CONVD 2560
#define N_G 1024
#define N_NH 3584  // CONVD + G

#define C_E2 2.88539008f     // 2/ln2 : tanh(x) = 1 - 2/(2^(C_E2*x)+1)
#define C_E2_INV 0.34657359f // ln2/2

__device__ __forceinline__ u16 f2bf(float f) {
  u32 u = __float_as_uint(f);
  u32 r = (u + 0x7FFFu + ((u >> 16) & 1u)) >> 16;
  return (u16)r;
}
__device__ __forceinline__ float fsigmoid(float x) {
  return __builtin_amdgcn_rcpf(1.f + __builtin_amdgcn_exp2f(-1.44269504f * x));
}
// pack two f32 -> two bf16 (round-half-up) in one u32 via v_perm (NO inline-asm cvt_pk:
// m240 says the asm form inhibits scheduling; R6 isolates this from the reduce-move)
__device__ __forceinline__ u32 pack_bf16_rhu(float a, float b) {
  u32 ua = __float_as_uint(a) + 0x8000u;
  u32 ub = __float_as_uint(b) + 0x8000u;
  return __builtin_amdgcn_perm(ub, ua, 0x07060302u);
}
// async 16B global -> LDS DMA (wave-uniform LDS base + lane*16; dest must be linear)
__device__ __forceinline__ void gload_lds16(const void* g, void* l) {
  __builtin_amdgcn_global_load_lds((const __attribute__((address_space(1))) unsigned int*)g,
                                   (__attribute__((address_space(3))) unsigned int*)l, 16, 0, 0);
}
// 16-lane-row prefix sum; lane m16==15 holds the row total
__device__ __forceinline__ float row16_prefix_sum(float pr) {
  pr += __int_as_float(__builtin_amdgcn_update_dpp(0, __float_as_int(pr), 0x111, 0xF, 0xF, true));
  pr += __int_as_float(__builtin_amdgcn_update_dpp(0, __float_as_int(pr), 0x112, 0xF, 0xF, true));
  pr += __int_as_float(__builtin_amdgcn_update_dpp(0, __float_as_int(pr), 0x114, 0xF, 0xF, true));
  pr += __int_as_float(__builtin_amdgcn_update_dpp(0, __float_as_int(pr), 0x118, 0xF, 0xF, true));
  return pr;
}

// ---------------- fused prep: 3x f32->bf16 convert + W transpose/pre-scale ----------------
// grid layout: [0,4096) x->xb | [4096,11264) w_in->wib | [11264,13312) wo->wob |
//              [13312,13824) wtprep
__global__ void prep_kernel(const float* __restrict__ x, u16* __restrict__ xb,
                            const float* __restrict__ w_in, u16* __restrict__ wib,
                            const float* __restrict__ wo, u16* __restrict__ wob,
                            const float* __restrict__ sw, u16* __restrict__ wtb) {
  int bid = blockIdx.x;
  if (bid < 11264) {
    const float* src;
    u16* dst;
    int i4;
    if (bid < 4096) { src = x; dst = xb; i4 = (bid * 256 + threadIdx.x) * 4; }
    else { src = w_in; dst = wib; i4 = ((bid - 4096) * 256 + threadIdx.x) * 4; }
    float4 v = *(const float4*)&src[i4];
    dst[i4 + 0] = f2bf(v.x);
    dst[i4 + 1] = f2bf(v.y);
    dst[i4 + 2] = f2bf(v.z);
    dst[i4 + 3] = f2bf(v.w);
  } else if (bid < 13312) {
    int i4 = ((bid - 11264) * 256 + threadIdx.x) * 4;
    float4 v = *(const float4*)&wo[i4];
    wob[i4 + 0] = f2bf(v.x);
    wob[i4 + 1] = f2bf(v.y);
    wob[i4 + 2] = f2bf(v.z);
    wob[i4 + 3] = f2bf(v.w);
  } else {
    int idx = (bid - 13312) * 256 + threadIdx.x;  // h*16384 + j*128 + v
    int h = idx >> 14;
    int rem = idx & 16383;
    int j = rem >> 7, v = rem & 127;
    wtb[idx] = f2bf(C_E2 * sw[((size_t)h * 128 + v) * 128 + j]);
  }
}

// ---------------- bf16 NT GEMM: C[M][N] = A[M][K] * B[N][K]^T (+bias) ----------------
// Staging via global_load_lds width=16 (m97 technique).
__global__ __launch_bounds__(256, 2) void gemm_bt(const u16* __restrict__ A,
                                                  const u16* __restrict__ B,
                                                  const float* __restrict__ bias,
                                                  float* __restrict__ C, int M, int N, int K) {
  const int tid = threadIdx.x;
  const int lane = tid & 63, w = tid >> 6;
  const int u = lane >> 4, m16 = lane & 15;
  const int wm = w & 1, wn = w >> 1;
  const int m0 = blockIdx.y * 128, n0 = blockIdx.x * 128;

  __shared__ __align__(16) u16 As[128 * 32];
  __shared__ __align__(16) u16 Bs[128 * 32];

  f32x4 acc[4][4];
#pragma unroll
  for (int i = 0; i < 4; ++i)
#pragma unroll
    for (int j = 0; j < 4; ++j)
#pragma unroll
      for (int r = 0; r < 4; ++r) acc[i][j][r] = 0.f;

  for (int kk = 0; kk < K; kk += 32) {
#pragma unroll
    for (int q = 0; q < 2; ++q) {
      int chunk = tid + 256 * q;
      int row = chunk >> 2, col = (chunk & 3) * 8;
      gload_lds16(&A[(size_t)(m0 + row) * K + kk + col], &As[row * 32 + col]);
      gload_lds16(&B[(size_t)(n0 + row) * K + kk + col], &Bs[row * 32 + col]);
    }
    __syncthreads();  // drains vmcnt (global_load_lds) + lgkmcnt
    short8 af[4], bfr[4];
#pragma unroll
    for (int i = 0; i < 4; ++i) af[i] = *(const short8*)&As[(64 * wm + 16 * i + m16) * 32 + 8 * u];
#pragma unroll
    for (int i = 0; i < 4; ++i) bfr[i] = *(const short8*)&Bs[(64 * wn + 16 * i + m16) * 32 + 8 * u];
#pragma unroll
    for (int am = 0; am < 4; ++am)
#pragma unroll
      for (int bn = 0; bn < 4; ++bn)
        acc[am][bn] = __builtin_amdgcn_mfma_f32_16x16x32_bf16(af[am], bfr[bn], acc[am][bn], 0, 0, 0);
    __syncthreads();
  }
#pragma unroll
  for (int am = 0; am < 4; ++am)
#pragma unroll
    for (int bn = 0; bn < 4; ++bn) {
      int n = n0 + 64 * wn + 16 * bn + m16;
      float bv = bias ? bias[n] : 0.f;
#pragma unroll
      for (int r = 0; r < 4; ++r) {
        int m = m0 + 64 * wm + 16 * am + 4 * u + r;
        C[(size_t)m * N + n] = acc[am][bn][r] + bv;
      }
    }
}

// ---------------- depthwise causal conv (K=4) + SiLU + scatter to scan layout ----------------
// SCIN[b*8+h][t][320]: q[0,64) k[64,128) g/f[128,192) v[192,320)
// v-slots are pre-scaled by 2/ln2 (folded into the scan's exp2 argument).
__global__ void conv_kernel(const float* __restrict__ h, const float* __restrict__ cw,
                            const float* __restrict__ cb, float* __restrict__ SCIN) {
  int gid = blockIdx.x * 256 + threadIdx.x;
  if (gid >= N_B * N_S * N_CONVD) return;
  int c = gid % N_CONVD;
  int bt = gid / N_CONVD;
  int t = bt & 1023, b = bt >> 10;
  float4 wv = *(const float4*)&cw[c * 4];
  const float* wvp = (const float*)&wv;
  float acc = cb[c];
#pragma unroll
  for (int j = 0; j < 4; ++j) {
    int tt = t - 3 + j;
    if (tt >= 0) acc += wvp[j] * h[((size_t)(b * 1024 + tt)) * N_NH + c];
  }
  float yv = acc * fsigmoid(acc);  // silu
  if (c >= 1024 && c < 2048) yv *= C_E2;  // pre-scale v for the scan
  int hh, off;
  if (c < 512) { hh = c >> 6; off = c & 63; }
  else if (c < 1024) { int cc = c - 512; hh = cc >> 6; off = 64 + (cc & 63); }
  else if (c < 2048) { int cc = c - 1024; hh = cc >> 7; off = 192 + (cc & 127); }
  else { int cc = c - 2048; hh = cc >> 6; off = 128 + (cc & 63); }
  SCIN[(((size_t)(b * 8 + hh)) * 1024 + t) * 320 + off] = yv;
}

// ---------------- k-normalize + forget-gate -> g (in place) ----------------
__global__ void prep2_kernel(float* __restrict__ SCIN, const float* __restrict__ fm,
                             const float* __restrict__ fb) {
  int widx = blockIdx.x * 4 + (threadIdx.x >> 6);  // one wave per (chain, t)
  int lane = threadIdx.x & 63;
  int chain = widx >> 10, t = widx & 1023;
  int hh = chain & 7;
  float* base = SCIN + ((size_t)chain * 1024 + t) * 320;
  float kv = base[64 + lane];
  float s = kv * kv;
#pragma unroll
  for (int m = 1; m < 64; m <<= 1) s += __shfl_xor(s, m, 64);
  float inv = __builtin_amdgcn_rsqf(s + 1e-12f);
  base[64 + lane] = kv * inv;
  float fv = base[128 + lane];
  float scale2 = 2.f * fsigmoid(fm[hh]);
  base[128 + lane] = fsigmoid(scale2 * (fv + fb[hh * 64 + lane]));
}

// ---------------- the sequential RSA scan ----------------
// Round-0 structure (proven 435 us): 64 WGs = 16 chains x 4 i-groups, 512 threads =
// 8 waves; wave wv owns j-cols [16wv,16wv+16); lane (u,m16) holds S[i=m16][j=16wv+4u+r];
// bf16 S tile double-buffered in LDS as MFMA B operand; LDS-only barrier.
// R6 single-variable experiment: y DPP-reduce + store of step t-1 moved POST-barrier
// into step t's ds_read latency shadow (the R4 idea), but with pack_bf16_rhu (v_perm)
// instead of R4's inline-asm cvt_pk (m240: asm form inhibits scheduling). If R4's +90us
// was the cvt_pk, this gains ~60-100cy/step; if it was the reduce-move, this repeats 525.
__global__ __launch_bounds__(512, 2) void scan_kernel(const u16* __restrict__ Wtb,
                                                      const float* __restrict__ SCIN,
                                                      float* __restrict__ Ybp) {
  const int tid = threadIdx.x;
  const int lane = tid & 63, wv = tid >> 6;  // wv = j-tile, 0..7
  const int u = lane >> 4, m16 = lane & 15;
  const int chain = blockIdx.x >> 2;
  const int ig = blockIdx.x & 3;  // dk row group: global i = 16*ig + m16
  const int hh = chain & 7;

  __shared__ __align__(16) u16 Slds[2][16 * 136];  // bf16 S tile, double-buffered

  // A-frag: A[m=m16][k=8u+idx] = Wt[hh][16wv+m16][32kc+8u+idx] (pre-scaled by 2/ln2)
  short8 Wfrag[4];
  {
    const u16* wb = Wtb + ((size_t)hh * 128 + (16 * wv + m16)) * 128 + 8 * u;
#pragma unroll
    for (int kc = 0; kc < 4; ++kc) Wfrag[kc] = *(const short8*)(wb + 32 * kc);
  }

  for (int x = tid; x < 2 * 16 * 136; x += 512) ((u16*)Slds)[x] = 0;

  const float* scin_c = SCIN + (size_t)chain * 1024 * 320;
  float* ybase = Ybp + ((size_t)(chain * 4 + ig)) * 1024 * 128;

  float Sreg[4] = {0.f, 0.f, 0.f, 0.f};
  float pp[4];  // previous step's q*S partials (reduced/stored post-barrier)

  // t=0 inputs (registers, no LDS staging)
  float qv = scin_c[16 * ig + m16];
  float kv = scin_c[64 + 16 * ig + m16];
  float gv = scin_c[128 + 16 * ig + m16];
  f32x4 cv = *(const f32x4*)&scin_c[192 + 16 * wv + 4 * u];  // = (2/ln2)*v[j]

  __syncthreads();

  for (int t = 0; t < 1024; ++t) {
    const u16* Sr = Slds[t & 1];
    u16* Sw = Slds[(t + 1) & 1];

    // B-frags first: B[k=8u+idx][n=m16] = S[m16][32kc+8u+idx]  (static indices only)
    short8 Bfrag[4];
#pragma unroll
    for (int kc = 0; kc < 4; ++kc)
      Bfrag[kc] = *(const short8*)&Sr[m16 * 136 + 32 * kc + 8 * u];

    // prefetch t+1 inputs (stay in flight across this step)
    const int tn = (t + 1) & 1023;
    const float* pn = scin_c + (size_t)tn * 320;
    float qn = pn[16 * ig + m16];
    float kn = pn[64 + 16 * ig + m16];
    float gn = pn[128 + 16 * ig + m16];
    f32x4 cn = *(const f32x4*)&pn[192 + 16 * wv + 4 * u];

    // pipelined y-reduction + store for step t-1 (fills the B-frag read latency /
    // LDS queue-drain window; all 8 waves are otherwise stalled here)
    if (t) {
#pragma unroll
      for (int r = 0; r < 4; ++r) pp[r] = row16_prefix_sum(pp[r]);
      if (m16 == 15) {
        f32x4 yo;
#pragma unroll
        for (int r = 0; r < 4; ++r) yo[r] = pp[r];
        *(f32x4*)(ybase + (size_t)(t - 1) * 128 + 16 * wv + 4 * u) = yo;
      }
    }

    // X[j=16wv+4u+r][i=m16]; acc starts at (2/ln2)*v so a0+a1 = exp2 argument
    f32x4 a0 = cv, a1 = {0.f, 0.f, 0.f, 0.f};
    a0 = __builtin_amdgcn_mfma_f32_16x16x32_bf16(Wfrag[0], Bfrag[0], a0, 0, 0, 0);
    a1 = __builtin_amdgcn_mfma_f32_16x16x32_bf16(Wfrag[1], Bfrag[1], a1, 0, 0, 0);
    a0 = __builtin_amdgcn_mfma_f32_16x16x32_bf16(Wfrag[2], Bfrag[2], a0, 0, 0, 0);
    a1 = __builtin_amdgcn_mfma_f32_16x16x32_bf16(Wfrag[3], Bfrag[3], a1, 0, 0, 0);

    // S update: tanh(x) = 1 - 2/(2^arg + 1), arg already in acc
#pragma unroll
    for (int r = 0; r < 4; ++r) {
      float e = __builtin_amdgcn_exp2f(a0[r] + a1[r]);
      float cand = 1.f - 2.f * __builtin_amdgcn_rcpf(e + 1.f);
      Sreg[r] = gv * Sreg[r] + kv * cand;
    }

    // pack + write first (starts the LDS write draining), then the p partials
    uint2 pck;
    pck.x = pack_bf16_rhu(Sreg[0], Sreg[1]);
    pck.y = pack_bf16_rhu(Sreg[2], Sreg[3]);
    *(uint2*)&Sw[m16 * 136 + 16 * wv + 4 * u] = pck;

#pragma unroll
    for (int r = 0; r < 4; ++r) pp[r] = qv * Sreg[r];

    // LDS-only barrier: global stores/loads stay in flight (no vmcnt drain)
    asm volatile("s_waitcnt lgkmcnt(0)\n\ts_barrier" ::: "memory");

    qv = qn; kv = kn; gv = gn; cv = cn;
  }

  // epilogue: y for t=1023
#pragma unroll
  for (int r = 0; r < 4; ++r) pp[r] = row16_prefix_sum(pp[r]);
  if (m16 == 15) {
    f32x4 yo;
#pragma unroll
    for (int r = 0; r < 4; ++r) yo[r] = pp[r];
    *(f32x4*)(ybase + (size_t)1023 * 128 + 16 * wv + 4 * u) = yo;
  }
}

// ---------------- sum y partials, (y + v*D)*silu(gate), RMSNorm, *g_w -> bf16 ----------------
__global__ __launch_bounds__(256, 2) void post_kernel(const float* __restrict__ Ybp,
                                                      const float* __restrict__ SCIN,
                                                      const float* __restrict__ h,
                                                      const float* __restrict__ Dp,
                                                      const float* __restrict__ gwv,
                                                      u16* __restrict__ Zb) {
  const int bt = blockIdx.x;
  const int b = bt >> 10, t = bt & 1023;
  const int lane = threadIdx.x & 63, wvi = threadIdx.x >> 6;
  float z[4];
  float ss = 0.f;
#pragma unroll
  for (int c = 0; c < 4; ++c) {
    int j = threadIdx.x + 256 * c;
    int head = j >> 7, dv = j & 127;
    int chain = b * 8 + head;
    float y = 0.f;
#pragma unroll
    for (int igx = 0; igx < 4; ++igx)
      y += Ybp[(((size_t)(chain * 4 + igx)) * 1024 + t) * 128 + dv];
    float v = SCIN[((size_t)chain * 1024 + t) * 320 + 192 + dv];  // = (2/ln2)*v_true
    float gate = h[((size_t)(b * 1024 + t)) * N_NH + 2560 + j];
    float zz = (y + v * (Dp[j] * C_E2_INV)) * (gate * fsigmoid(gate));
    z[c] = zz;
    ss += zz * zz;
  }
#pragma unroll
  for (int m = 1; m < 64; m <<= 1) ss += __shfl_xor(ss, m, 64);
  __shared__ float red[4];
  if (lane == 0) red[wvi] = ss;
  __syncthreads();
  float tot = red[0] + red[1] + red[2] + red[3];
  float scale = __builtin_amdgcn_rsqf(tot * (1.f / 1024.f) + 1e-6f);
#pragma unroll
  for (int c = 0; c < 4; ++c) {
    int j = threadIdx.x + 256 * c;
    Zb[(size_t)(b * 1024 + t) * 1024 + j] = f2bf(z[c] * scale * gwv[j]);
  }
}

extern "C" void kernel_launch(void* const* d_in, const int* in_sizes, int n_in,
                              void* d_out, int out_size, void* d_ws, size_t ws_size,
                              hipStream_t stream) {
  const float* x    = (const float*)d_in[0];
  const float* w_in = (const float*)d_in[1];
  const float* b_in = (const float*)d_in[2];
  const float* cw   = (const float*)d_in[3];
  const float* cb   = (const float*)d_in[4];
  const float* Dp   = (const float*)d_in[5];
  const float* sw   = (const float*)d_in[6];
  const float* fm   = (const float*)d_in[7];
  const float* fb   = (const float*)d_in[8];
  const float* gwv  = (const float*)d_in[9];
  const float* wo   = (const float*)d_in[10];
  float* out = (float*)d_out;

  char* p = (char*)d_ws;
  auto alloc = [&](size_t bytes) {
    char* r = p;
    p += (bytes + 255) & ~(size_t)255;
    return r;
  };
  u16* xb    = (u16*)alloc((size_t)2048 * 2048 * 2);
  u16* wib   = (u16*)alloc((size_t)3584 * 2048 * 2);
  u16* wob   = (u16*)alloc((size_t)2048 * 1024 * 2);
  u16* wtb   = (u16*)alloc((size_t)8 * 128 * 128 * 2);
  float* hbf = (float*)alloc((size_t)2048 * 3584 * 4);
  float* scin= (float*)alloc((size_t)16 * 1024 * 320 * 4);
  float* ybp = (float*)alloc((size_t)64 * 1024 * 128 * 4);
  u16* zb    = (u16*)alloc((size_t)2048 * 1024 * 2);

  // fused: cvt(x) + cvt(w_in) + cvt(wo) + wtprep
  prep_kernel<<<13824, 256, 0, stream>>>(x, xb, w_in, wib, wo, wob, sw, wtb);

  // h = x @ w_in^T + b_in
  gemm_bt<<<dim3(3584 / 128, 2048 / 128), 256, 0, stream>>>(xb, wib, b_in, hbf, 2048, 3584, 2048);

  conv_kernel<<<(N_B * N_S * N_CONVD) / 256, 256, 0, stream>>>(hbf, cw, cb, scin);
  prep2_kernel<<<(16 * 1024) / 4, 256, 0, stream>>>(scin, fm, fb);

  // proven shape: 64 WGs x 512 threads, one (chain, ig) unit per WG
  scan_kernel<<<64, 512, 0, stream>>>(wtb, scin, ybp);

  post_kernel<<<2048, 256, 0, stream>>>(ybp, scin, hbf, Dp, gwv, zb);

  // out = z @ w_out^T
  gemm_bt<<<dim3(2048 / 128, 2048 / 128), 256, 0, stream>>>(zb, wob, nullptr, out, 2048, 2048, 1024);
}

// Round 7
// 640.955 us; speedup vs baseline: 1.1651x; 1.1651x over previous
//
#include <hip/hip_runtime.h>

typedef unsigned short u16;
typedef unsigned int u32;
typedef __attribute__((ext_vector_type(8))) short short8;
typedef __attribute__((ext_vector_type(4))) float f32x4;

// Problem constants
#define N_B 2
#define N_S 1024
#define N_DIN 2048
#define N_DOUT 2048
#define N_H 8
#define N_DK 64
#define N_DV 128
#define N_CONVD 2560
#define N_G 1024
#define N_NH 3584  // CONVD + G

#define C_E2 2.88539008f     // 2/ln2 : tanh(x) = 1 - 2/(2^(C_E2*x)+1)
#define C_E2_INV 0.34657359f // ln2/2

__device__ __forceinline__ u16 f2bf(float f) {
  u32 u = __float_as_uint(f);
  u32 r = (u + 0x7FFFu + ((u >> 16) & 1u)) >> 16;
  return (u16)r;
}
__device__ __forceinline__ float fsigmoid(float x) {
  return __builtin_amdgcn_rcpf(1.f + __builtin_amdgcn_exp2f(-1.44269504f * x));
}
// pack two f32 -> two bf16 (round-half-up) in one u32 via v_perm
__device__ __forceinline__ u32 pack_bf16_rhu(float a, float b) {
  u32 ua = __float_as_uint(a) + 0x8000u;
  u32 ub = __float_as_uint(b) + 0x8000u;
  return __builtin_amdgcn_perm(ub, ua, 0x07060302u);
}
// async 16B global -> LDS DMA (wave-uniform LDS base + lane*16; dest must be linear)
__device__ __forceinline__ void gload_lds16(const void* g, void* l) {
  __builtin_amdgcn_global_load_lds((const __attribute__((address_space(1))) unsigned int*)g,
                                   (__attribute__((address_space(3))) unsigned int*)l, 16, 0, 0);
}

// ---------------- fused prep: 3x f32->bf16 convert + W transpose/pre-scale ----------------
// grid layout: [0,4096) x->xb | [4096,11264) w_in->wib | [11264,13312) wo->wob |
//              [13312,13824) wtprep
__global__ void prep_kernel(const float* __restrict__ x, u16* __restrict__ xb,
                            const float* __restrict__ w_in, u16* __restrict__ wib,
                            const float* __restrict__ wo, u16* __restrict__ wob,
                            const float* __restrict__ sw, u16* __restrict__ wtb) {
  int bid = blockIdx.x;
  if (bid < 11264) {
    const float* src;
    u16* dst;
    int i4;
    if (bid < 4096) { src = x; dst = xb; i4 = (bid * 256 + threadIdx.x) * 4; }
    else { src = w_in; dst = wib; i4 = ((bid - 4096) * 256 + threadIdx.x) * 4; }
    float4 v = *(const float4*)&src[i4];
    dst[i4 + 0] = f2bf(v.x);
    dst[i4 + 1] = f2bf(v.y);
    dst[i4 + 2] = f2bf(v.z);
    dst[i4 + 3] = f2bf(v.w);
  } else if (bid < 13312) {
    int i4 = ((bid - 11264) * 256 + threadIdx.x) * 4;
    float4 v = *(const float4*)&wo[i4];
    wob[i4 + 0] = f2bf(v.x);
    wob[i4 + 1] = f2bf(v.y);
    wob[i4 + 2] = f2bf(v.z);
    wob[i4 + 3] = f2bf(v.w);
  } else {
    int idx = (bid - 13312) * 256 + threadIdx.x;  // h*16384 + j*128 + v
    int h = idx >> 14;
    int rem = idx & 16383;
    int j = rem >> 7, v = rem & 127;
    wtb[idx] = f2bf(C_E2 * sw[((size_t)h * 128 + v) * 128 + j]);
  }
}

// ---------------- bf16 NT GEMM: C[M][N] = A[M][K] * B[N][K]^T (+bias) ----------------
// Staging via global_load_lds width=16 (m97 technique).
__global__ __launch_bounds__(256, 2) void gemm_bt(const u16* __restrict__ A,
                                                  const u16* __restrict__ B,
                                                  const float* __restrict__ bias,
                                                  float* __restrict__ C, int M, int N, int K) {
  const int tid = threadIdx.x;
  const int lane = tid & 63, w = tid >> 6;
  const int u = lane >> 4, m16 = lane & 15;
  const int wm = w & 1, wn = w >> 1;
  const int m0 = blockIdx.y * 128, n0 = blockIdx.x * 128;

  __shared__ __align__(16) u16 As[128 * 32];
  __shared__ __align__(16) u16 Bs[128 * 32];

  f32x4 acc[4][4];
#pragma unroll
  for (int i = 0; i < 4; ++i)
#pragma unroll
    for (int j = 0; j < 4; ++j)
#pragma unroll
      for (int r = 0; r < 4; ++r) acc[i][j][r] = 0.f;

  for (int kk = 0; kk < K; kk += 32) {
#pragma unroll
    for (int q = 0; q < 2; ++q) {
      int chunk = tid + 256 * q;
      int row = chunk >> 2, col = (chunk & 3) * 8;
      gload_lds16(&A[(size_t)(m0 + row) * K + kk + col], &As[row * 32 + col]);
      gload_lds16(&B[(size_t)(n0 + row) * K + kk + col], &Bs[row * 32 + col]);
    }
    __syncthreads();  // drains vmcnt (global_load_lds) + lgkmcnt
    short8 af[4], bfr[4];
#pragma unroll
    for (int i = 0; i < 4; ++i) af[i] = *(const short8*)&As[(64 * wm + 16 * i + m16) * 32 + 8 * u];
#pragma unroll
    for (int i = 0; i < 4; ++i) bfr[i] = *(const short8*)&Bs[(64 * wn + 16 * i + m16) * 32 + 8 * u];
#pragma unroll
    for (int am = 0; am < 4; ++am)
#pragma unroll
      for (int bn = 0; bn < 4; ++bn)
        acc[am][bn] = __builtin_amdgcn_mfma_f32_16x16x32_bf16(af[am], bfr[bn], acc[am][bn], 0, 0, 0);
    __syncthreads();
  }
#pragma unroll
  for (int am = 0; am < 4; ++am)
#pragma unroll
    for (int bn = 0; bn < 4; ++bn) {
      int n = n0 + 64 * wn + 16 * bn + m16;
      float bv = bias ? bias[n] : 0.f;
#pragma unroll
      for (int r = 0; r < 4; ++r) {
        int m = m0 + 64 * wm + 16 * am + 4 * u + r;
        C[(size_t)m * N + n] = acc[am][bn][r] + bv;
      }
    }
}

// ---------------- FUSED depthwise causal conv (K=4) + SiLU + k-norm + f->g + scatter -----
// One block per (b,t). Conv outputs staged in LDS; k-normalization per head by 32-lane
// half-waves (shfl_xor masks <=16 stay within the half-wave); then direct scatter into
// SCIN[b*8+h][t][320]: q[0,64) k[64,128) g[128,192) v[192,320)  (v pre-scaled by 2/ln2).
// Replaces conv_kernel + prep2_kernel (saves a 16MB SCIN round-trip + one dispatch).
__global__ __launch_bounds__(256) void convprep_kernel(const float* __restrict__ h,
                                                       const float* __restrict__ cw,
                                                       const float* __restrict__ cb,
                                                       const float* __restrict__ fm,
                                                       const float* __restrict__ fb,
                                                       float* __restrict__ SCIN) {
  const int bt = blockIdx.x;
  const int t = bt & 1023, b = bt >> 10;
  const int tid = threadIdx.x;
  __shared__ float ch[N_CONVD];

  // phase 1: conv + silu for 10 channels per thread (stride-256 for coalescing)
#pragma unroll
  for (int cc = 0; cc < 10; ++cc) {
    int c = tid + 256 * cc;
    float4 cwv = *(const float4*)&cw[c * 4];
    const float* cwp = (const float*)&cwv;
    float acc = cb[c];
#pragma unroll
    for (int j = 0; j < 4; ++j) {
      int tt = t - 3 + j;
      if (tt >= 0) acc += cwp[j] * h[((size_t)(b * 1024 + tt)) * N_NH + c];
    }
    ch[c] = acc * fsigmoid(acc);  // silu
  }
  __syncthreads();

  // phase 2: each 32-lane half-wave owns one head hh = tid>>5
  const int hh = tid >> 5, l = tid & 31;
  float* chainbase = SCIN + ((size_t)(b * 8 + hh) * 1024 + t) * 320;

  // k-normalize (channels 512 + 64*hh + [0,64))
  float k0 = ch[512 + 64 * hh + l], k1 = ch[512 + 64 * hh + 32 + l];
  float s = k0 * k0 + k1 * k1;
#pragma unroll
  for (int m = 1; m < 32; m <<= 1) s += __shfl_xor(s, m, 64);
  float inv = __builtin_amdgcn_rsqf(s + 1e-12f);
  chainbase[64 + l] = k0 * inv;
  chainbase[64 + 32 + l] = k1 * inv;

  // f -> g (channels 2048 + 64*hh + [0,64))
  float sc2 = 2.f * fsigmoid(fm[hh]);
  float f0 = ch[2048 + 64 * hh + l], f1 = ch[2048 + 64 * hh + 32 + l];
  chainbase[128 + l] = fsigmoid(sc2 * (f0 + fb[hh * 64 + l]));
  chainbase[128 + 32 + l] = fsigmoid(sc2 * (f1 + fb[hh * 64 + 32 + l]));

  // q (channels 64*hh + [0,64))
  chainbase[l] = ch[64 * hh + l];
  chainbase[32 + l] = ch[64 * hh + 32 + l];

  // v (channels 1024 + 128*hh + [0,128)), pre-scaled by 2/ln2
  chainbase[192 + l] = ch[1024 + 128 * hh + l] * C_E2;
  chainbase[192 + 32 + l] = ch[1024 + 128 * hh + 32 + l] * C_E2;
  chainbase[192 + 64 + l] = ch[1024 + 128 * hh + 64 + l] * C_E2;
  chainbase[192 + 96 + l] = ch[1024 + 128 * hh + 96 + l] * C_E2;
}

// ---------------- the sequential RSA scan ----------------
// EXACT R5 structure (proven 438 us): 64 WGs = 16 chains x 4 i-groups, 512 threads =
// 8 waves; wave wv owns j-cols [16wv,16wv+16); lane (u,m16) holds S[i=m16][j=16wv+4u+r];
// bf16 S tile double-buffered in LDS as MFMA B operand; same-iteration DPP y-reduce
// (R4/R6 proved post-barrier reduce costs +95us); LDS-only barrier.
// Single change: S' = fma(-2k, rcp(e+1), fma(g,S,k)) — the fma(g,S,k) term computes
// in parallel with the exp2/rcp chain (7 -> 5 dependent ops), algebraically identical.
__global__ __launch_bounds__(512, 2) void scan_kernel(const u16* __restrict__ Wtb,
                                                      const float* __restrict__ SCIN,
                                                      float* __restrict__ Ybp) {
  const int tid = threadIdx.x;
  const int lane = tid & 63, wv = tid >> 6;  // wv = j-tile, 0..7
  const int u = lane >> 4, m16 = lane & 15;
  const int chain = blockIdx.x >> 2;
  const int ig = blockIdx.x & 3;  // dk row group: global i = 16*ig + m16
  const int hh = chain & 7;

  __shared__ __align__(16) u16 Slds[2][16 * 136];  // bf16 S tile, double-buffered

  // A-frag: A[m=m16][k=8u+idx] = Wt[hh][16wv+m16][32kc+8u+idx] (pre-scaled by 2/ln2)
  short8 Wfrag[4];
  {
    const u16* wb = Wtb + ((size_t)hh * 128 + (16 * wv + m16)) * 128 + 8 * u;
#pragma unroll
    for (int kc = 0; kc < 4; ++kc) Wfrag[kc] = *(const short8*)(wb + 32 * kc);
  }

  for (int x = tid; x < 2 * 16 * 136; x += 512) ((u16*)Slds)[x] = 0;

  const float* scin_c = SCIN + (size_t)chain * 1024 * 320;
  float* ybase = Ybp + ((size_t)(chain * 4 + ig)) * 1024 * 128;

  float Sreg[4] = {0.f, 0.f, 0.f, 0.f};

  // t=0 inputs (registers, no LDS staging)
  float qv = scin_c[16 * ig + m16];
  float kv = scin_c[64 + 16 * ig + m16];
  float gv = scin_c[128 + 16 * ig + m16];
  f32x4 cv = *(const f32x4*)&scin_c[192 + 16 * wv + 4 * u];  // = (2/ln2)*v[j]

  __syncthreads();

  for (int t = 0; t < 1024; ++t) {
    // prefetch t+1 inputs into registers (stay in flight across the barrier)
    const int tn = (t + 1) & 1023;
    const float* pn = scin_c + (size_t)tn * 320;
    float qn = pn[16 * ig + m16];
    float kn = pn[64 + 16 * ig + m16];
    float gn = pn[128 + 16 * ig + m16];
    f32x4 cn = *(const f32x4*)&pn[192 + 16 * wv + 4 * u];

    const u16* Sr = Slds[t & 1];
    u16* Sw = Slds[(t + 1) & 1];

    // B-frag: B[k=8u+idx][n=m16] = S[m16][32kc+8u+idx]
    short8 Bfrag[4];
#pragma unroll
    for (int kc = 0; kc < 4; ++kc)
      Bfrag[kc] = *(const short8*)&Sr[m16 * 136 + 32 * kc + 8 * u];

    // X[j=16wv+4u+r][i=m16]; acc starts at (2/ln2)*v so a0+a1 = exp2 argument
    f32x4 a0 = cv, a1 = {0.f, 0.f, 0.f, 0.f};
    a0 = __builtin_amdgcn_mfma_f32_16x16x32_bf16(Wfrag[0], Bfrag[0], a0, 0, 0, 0);
    a1 = __builtin_amdgcn_mfma_f32_16x16x32_bf16(Wfrag[1], Bfrag[1], a1, 0, 0, 0);
    a0 = __builtin_amdgcn_mfma_f32_16x16x32_bf16(Wfrag[2], Bfrag[2], a0, 0, 0, 0);
    a1 = __builtin_amdgcn_mfma_f32_16x16x32_bf16(Wfrag[3], Bfrag[3], a1, 0, 0, 0);

    const float k2n = -2.f * kv;  // hoistable per step
    float p[4];
#pragma unroll
    for (int r = 0; r < 4; ++r) {
      float base = __builtin_fmaf(gv, Sreg[r], kv);             // parallel with exp2/rcp
      float e = __builtin_amdgcn_exp2f(a0[r] + a1[r]);          // e^{2x}
      float d = __builtin_amdgcn_rcpf(e + 1.f);
      Sreg[r] = __builtin_fmaf(k2n, d, base);                   // g*S + k*tanh(x)
      p[r] = qv * Sreg[r];
    }

    // bf16 S tile for next step's B operand (wave-exclusive j-columns)
    uint2 pck;
    pck.x = pack_bf16_rhu(Sreg[0], Sreg[1]);
    pck.y = pack_bf16_rhu(Sreg[2], Sreg[3]);
    *(uint2*)&Sw[m16 * 136 + 16 * wv + 4 * u] = pck;

    // partial y over this WG's 16 rows: DPP prefix-reduce over m16; lane 15 holds sum
#pragma unroll
    for (int r = 0; r < 4; ++r) {
      float pr = p[r];
      pr += __int_as_float(__builtin_amdgcn_update_dpp(0, __float_as_int(pr), 0x111, 0xF, 0xF, true));
      pr += __int_as_float(__builtin_amdgcn_update_dpp(0, __float_as_int(pr), 0x112, 0xF, 0xF, true));
      pr += __int_as_float(__builtin_amdgcn_update_dpp(0, __float_as_int(pr), 0x114, 0xF, 0xF, true));
      pr += __int_as_float(__builtin_amdgcn_update_dpp(0, __float_as_int(pr), 0x118, 0xF, 0xF, true));
      p[r] = pr;
    }
    if (m16 == 15) {
      f32x4 yo;
      yo[0] = p[0]; yo[1] = p[1]; yo[2] = p[2]; yo[3] = p[3];
      *(f32x4*)(ybase + (size_t)t * 128 + 16 * wv + 4 * u) = yo;  // fire-and-forget
    }

    // LDS-only barrier: global stores/loads stay in flight (no vmcnt drain)
    asm volatile("s_waitcnt lgkmcnt(0)\n\ts_barrier" ::: "memory");

    qv = qn; kv = kn; gv = gn; cv = cn;
  }
}

// ---------------- sum y partials, (y + v*D)*silu(gate), RMSNorm, *g_w -> bf16 ----------------
__global__ __launch_bounds__(256, 2) void post_kernel(const float* __restrict__ Ybp,
                                                      const float* __restrict__ SCIN,
                                                      const float* __restrict__ h,
                                                      const float* __restrict__ Dp,
                                                      const float* __restrict__ gwv,
                                                      u16* __restrict__ Zb) {
  const int bt = blockIdx.x;
  const int b = bt >> 10, t = bt & 1023;
  const int lane = threadIdx.x & 63, wvi = threadIdx.x >> 6;
  float z[4];
  float ss = 0.f;
#pragma unroll
  for (int c = 0; c < 4; ++c) {
    int j = threadIdx.x + 256 * c;
    int head = j >> 7, dv = j & 127;
    int chain = b * 8 + head;
    float y = 0.f;
#pragma unroll
    for (int igx = 0; igx < 4; ++igx)
      y += Ybp[(((size_t)(chain * 4 + igx)) * 1024 + t) * 128 + dv];
    float v = SCIN[((size_t)chain * 1024 + t) * 320 + 192 + dv];  // = (2/ln2)*v_true
    float gate = h[((size_t)(b * 1024 + t)) * N_NH + 2560 + j];
    float zz = (y + v * (Dp[j] * C_E2_INV)) * (gate * fsigmoid(gate));
    z[c] = zz;
    ss += zz * zz;
  }
#pragma unroll
  for (int m = 1; m < 64; m <<= 1) ss += __shfl_xor(ss, m, 64);
  __shared__ float red[4];
  if (lane == 0) red[wvi] = ss;
  __syncthreads();
  float tot = red[0] + red[1] + red[2] + red[3];
  float scale = __builtin_amdgcn_rsqf(tot * (1.f / 1024.f) + 1e-6f);
#pragma unroll
  for (int c = 0; c < 4; ++c) {
    int j = threadIdx.x + 256 * c;
    Zb[(size_t)(b * 1024 + t) * 1024 + j] = f2bf(z[c] * scale * gwv[j]);
  }
}

extern "C" void kernel_launch(void* const* d_in, const int* in_sizes, int n_in,
                              void* d_out, int out_size, void* d_ws, size_t ws_size,
                              hipStream_t stream) {
  const float* x    = (const float*)d_in[0];
  const float* w_in = (const float*)d_in[1];
  const float* b_in = (const float*)d_in[2];
  const float* cw   = (const float*)d_in[3];
  const float* cb   = (const float*)d_in[4];
  const float* Dp   = (const float*)d_in[5];
  const float* sw   = (const float*)d_in[6];
  const float* fm   = (const float*)d_in[7];
  const float* fb   = (const float*)d_in[8];
  const float* gwv  = (const float*)d_in[9];
  const float* wo   = (const float*)d_in[10];
  float* out = (float*)d_out;

  char* p = (char*)d_ws;
  auto alloc = [&](size_t bytes) {
    char* r = p;
    p += (bytes + 255) & ~(size_t)255;
    return r;
  };
  u16* xb    = (u16*)alloc((size_t)2048 * 2048 * 2);
  u16* wib   = (u16*)alloc((size_t)3584 * 2048 * 2);
  u16* wob   = (u16*)alloc((size_t)2048 * 1024 * 2);
  u16* wtb   = (u16*)alloc((size_t)8 * 128 * 128 * 2);
  float* hbf = (float*)alloc((size_t)2048 * 3584 * 4);
  float* scin= (float*)alloc((size_t)16 * 1024 * 320 * 4);
  float* ybp = (float*)alloc((size_t)64 * 1024 * 128 * 4);
  u16* zb    = (u16*)alloc((size_t)2048 * 1024 * 2);

  // fused: cvt(x) + cvt(w_in) + cvt(wo) + wtprep
  prep_kernel<<<13824, 256, 0, stream>>>(x, xb, w_in, wib, wo, wob, sw, wtb);

  // h = x @ w_in^T + b_in
  gemm_bt<<<dim3(3584 / 128, 2048 / 128), 256, 0, stream>>>(xb, wib, b_in, hbf, 2048, 3584, 2048);

  // fused conv + silu + k-norm + forget-gate + scatter
  convprep_kernel<<<2048, 256, 0, stream>>>(hbf, cw, cb, fm, fb, scin);

  // proven shape: 64 WGs x 512 threads, one (chain, ig) unit per WG
  scan_kernel<<<64, 512, 0, stream>>>(wtb, scin, ybp);

  post_kernel<<<2048, 256, 0, stream>>>(ybp, scin, hbf, Dp, gwv, zb);

  // out = z @ w_out^T
  gemm_bt<<<dim3(2048 / 128, 2048 / 128), 256, 0, stream>>>(zb, wob, nullptr, out, 2048, 2048, 1024);
}